// Round 9
// baseline (16.825 us; speedup 1.0000x reference)
//
#include <hip/hip_runtime.h>

// LogNorm moment-matching, v9: triangular flat-K f16 GEMM, 16-gene tiles,
// 5000 waves (TLP-first).
//
//   e = exp(Z_mu + sigma^2/2); x1' = e/4; x2' = e*sigma/4        (C x G)
//   var_num'[s,g] = sum_{d<=c} sc * (w_sc w_sd corr_cd) * (x2'_c x2'_d)
//   Ssum'[s,g]    = W @ x1'; var = vn'/ss'^2 (1/16 scale cancels);
//   mu = log(ss') + log4 - var/2 ; sigma = sqrt(var)
//
// v8 post-mortem: A-frag preload (96 VGPR) regressed -> not load-latency
// bound; v7's residual is TLP starvation (2500 waves = 2.4/SIMD) + phase
// convoying. v9: 16-gene tiles -> 1250 blocks x 4 waves = 5000 waves
// (4.9/SIMD), per-wave phases halved, in-loop A-loads kept (v7-style).
// Block covers all 96 triangular panels exactly once (p = i*4 + w).
//
// MFMA 16x16x32_f16, layout as verified v2-v8:
//   A-frag: lane(q,gl) = A[m=gl][k=q*8+j]   (m = state)
//   B-frag: lane(q,gl) = B[k=q*8+j][n=gl]   (n = gene)
//   C/D:    lane(q,gl) reg r = D[row=q*4+r][col=gl]

#define S_STATES 16
#define C_TYPES  64
#define G_GENES  20000
#define OUT_HALF (S_STATES * G_GENES)
#define NPAIR    96
#define PER_WAVE 24

typedef _Float16 f16x2 __attribute__((ext_vector_type(2)));
typedef _Float16 f16x8 __attribute__((ext_vector_type(8)));
typedef float    f32x4 __attribute__((ext_vector_type(4)));

union Frag8 { f16x2 p[4]; f16x8 v; uint4 u; _Float16 h[8]; };

// ---- Kernel P: frag-ordered f16 A panels (1 KB each; 98 KB total) ----
__global__ __launch_bounds__(64)
void build_A(const float* __restrict__ corr, const float* __restrict__ w,
             unsigned short* __restrict__ cwA)
{
    const int p    = blockIdx.x;          // 0..97
    const int lane = threadIdx.x;
    const int gl   = lane & 15;           // state (A row)
    const int q    = lane >> 4;
    Frag8 v;
    if (p < NPAIR) {
        const int dh = (p >= 64);
        const int c  = dh ? p - 32 : p;
        const int d0 = dh * 32 + q * 8;
        const float wc = w[gl * C_TYPES + c];
        const float4 c0 = *(const float4*)(corr + c * C_TYPES + d0);
        const float4 c1 = *(const float4*)(corr + c * C_TYPES + d0 + 4);
        const float4 w0 = *(const float4*)(w + gl * C_TYPES + d0);
        const float4 w1 = *(const float4*)(w + gl * C_TYPES + d0 + 4);
        const float cv[8] = {c0.x,c0.y,c0.z,c0.w,c1.x,c1.y,c1.z,c1.w};
        const float wv[8] = {w0.x,w0.y,w0.z,w0.w,w1.x,w1.y,w1.z,w1.w};
#pragma unroll
        for (int j = 0; j < 8; ++j) {
            const int d = d0 + j;
            const float sc = (d < c) ? 2.0f : (d == c ? 1.0f : 0.0f);
            v.h[j] = (_Float16)(sc * cv[j] * wc * wv[j]);
        }
    } else {                               // W panels for the Ssum GEMM
        const int k0 = (p - NPAIR) * 32 + q * 8;
        const float4 w0 = *(const float4*)(w + gl * C_TYPES + k0);
        const float4 w1 = *(const float4*)(w + gl * C_TYPES + k0 + 4);
        const float wv[8] = {w0.x,w0.y,w0.z,w0.w,w1.x,w1.y,w1.z,w1.w};
#pragma unroll
        for (int j = 0; j < 8; ++j) v.h[j] = (_Float16)wv[j];
    }
    *(uint4*)(cwA + (p << 9) + lane * 8) = v.u;
}

// ---- Kernel M: main ----
__global__ __launch_bounds__(256, 4)
void lognorm_main(const float* __restrict__ Z_mu,
                  const float* __restrict__ Z_sigma,
                  const unsigned short* __restrict__ cwA,
                  float* __restrict__ out)
{
    __shared__ f16x2 x2pT[16][35];       // [gene][d-pair]; ~2-way reads
    __shared__ f16x2 x1pT[16][35];
    __shared__ float accs[4][S_STATES][17];
    __shared__ float ssum_s[S_STATES][17];

    const int gt    = blockIdx.x;        // 0..1249, 16 genes (exact)
    const int tid   = threadIdx.x;
    const int w     = tid >> 6;          // wave id = K-interleave slot
    const int lane  = tid & 63;
    const int gl    = lane & 15;
    const int q     = lane >> 4;
    const int gbase = gt * 16;

    // Ssum W panels: wave 0 only, issued early to overlap X-phase
    Frag8 wf0, wf1;
    if (w == 0) {
        wf0.u = *(const uint4*)(cwA + ((NPAIR + 0) << 9) + lane * 8);
        wf1.u = *(const uint4*)(cwA + ((NPAIR + 1) << 9) + lane * 8);
    }

    // ---- X-phase: thread -> gene gx = tid&15, d-pairs (tid>>4), +16 ----
    {
        const int gx  = tid & 15;
        const int dpA = tid >> 4;        // 0..15
#pragma unroll
        for (int t = 0; t < 2; ++t) {
            const int dp = dpA + 16 * t;
            const float m0 = Z_mu   [(2*dp)     * G_GENES + gbase + gx];
            const float m1 = Z_mu   [(2*dp + 1) * G_GENES + gbase + gx];
            const float s0 = Z_sigma[(2*dp)     * G_GENES + gbase + gx];
            const float s1 = Z_sigma[(2*dp + 1) * G_GENES + gbase + gx];
            const float e0 = __expf(fmaf(0.5f * s0, s0, m0)) * 0.25f;
            const float e1 = __expf(fmaf(0.5f * s1, s1, m1)) * 0.25f;
            f16x2 a, b;
            a.x = (_Float16)(e0 * s0); a.y = (_Float16)(e1 * s1);
            b.x = (_Float16)e0;        b.y = (_Float16)e1;
            x2pT[gx][dp] = a;
            x1pT[gx][dp] = b;
        }
    }
    __syncthreads();

    // ---- xh: 8 LDS reads, reused 12x each ----
    f16x2 xh[2][4];                      // [dh][jp]
#pragma unroll
    for (int dh = 0; dh < 2; ++dh)
#pragma unroll
        for (int jp = 0; jp < 4; ++jp)
            xh[dh][jp] = x2pT[gl][dh * 16 + q * 4 + jp];

    // ---- K-loop: 24 x {A-load, ds_read xct, 4 pk_mul, 1 MFMA} ----
    // panel p = i*4 + w: dh = (i>=16); c = p - dh*32; dp = c>>1 has
    // compile-time offset 2i (+wq); component c&1 = w&1 (wave-uniform).
    const unsigned short* Abase = cwA + (w << 9) + lane * 8;
    const int wq = w >> 1;
    const int wc = w & 1;
    f32x4 acc0 = {0.f,0.f,0.f,0.f}, acc1 = {0.f,0.f,0.f,0.f};
#pragma unroll
    for (int i = 0; i < PER_WAVE; ++i) {
        Frag8 af; af.u = *(const uint4*)(Abase + (i << 11));
        const int dh = (i >= 16) ? 1 : 0;
        const int dp = 2*i - dh*16 + wq;
        const f16x2 pr = x2pT[gl][dp];   // conflict-free (4-way broadcast)
        const _Float16 xc = wc ? pr.y : pr.x;   // wave-uniform select
        f16x2 s; s.x = xc; s.y = xc;
        Frag8 b;
#pragma unroll
        for (int jp = 0; jp < 4; ++jp) b.p[jp] = s * xh[dh][jp];
        if (i & 1) acc1 = __builtin_amdgcn_mfma_f32_16x16x32_f16(af.v, b.v, acc1, 0, 0, 0);
        else       acc0 = __builtin_amdgcn_mfma_f32_16x16x32_f16(af.v, b.v, acc0, 0, 0, 0);
    }
    const f32x4 acc = acc0 + acc1;
#pragma unroll
    for (int r = 0; r < 4; ++r) accs[w][q*4 + r][gl] = acc[r];

    // ---- Ssum GEMM: wave 0, full 16x16 state-gene tile ----
    if (w == 0) {
        Frag8 x1f0, x1f1;
#pragma unroll
        for (int jp = 0; jp < 4; ++jp) {
            x1f0.p[jp] = x1pT[gl][q*4 + jp];
            x1f1.p[jp] = x1pT[gl][16 + q*4 + jp];
        }
        f32x4 sa = {0.f,0.f,0.f,0.f};
        sa = __builtin_amdgcn_mfma_f32_16x16x32_f16(wf0.v, x1f0.v, sa, 0, 0, 0);
        sa = __builtin_amdgcn_mfma_f32_16x16x32_f16(wf1.v, x1f1.v, sa, 0, 0, 0);
#pragma unroll
        for (int r = 0; r < 4; ++r) ssum_s[q*4 + r][gl] = sa[r];
    }
    __syncthreads();

    // ---- epilogue: thread -> (s = tid>>4, gene gx = tid&15) ----
    const int s  = tid >> 4;
    const int gx = tid & 15;
    const float vn = (accs[0][s][gx] + accs[1][s][gx])
                   + (accs[2][s][gx] + accs[3][s][gx]);
    const float ss   = ssum_s[s][gx];                 // = Ssum/4
    const float rvar = fmaxf(vn, 0.f) / (ss * ss);    // scale cancels
    out[s * G_GENES + gbase + gx] =
        __logf(ss) + 1.3862943611f - 0.5f * rvar;     // + log 4
    out[OUT_HALF + s * G_GENES + gbase + gx] = sqrtf(rvar);
}

extern "C" void kernel_launch(void* const* d_in, const int* in_sizes, int n_in,
                              void* d_out, int out_size, void* d_ws, size_t ws_size,
                              hipStream_t stream) {
    const float* Z_mu      = (const float*)d_in[0];
    const float* Z_sigma   = (const float*)d_in[1];
    const float* corr      = (const float*)d_in[2];
    const float* cell_prob = (const float*)d_in[3];
    float* out = (float*)d_out;
    unsigned short* cwA = (unsigned short*)d_ws;   // 98 KB frag-ordered f16 A

    build_A<<<dim3(NPAIR + 2), dim3(64), 0, stream>>>(corr, cell_prob, cwA);

    const int gtiles = G_GENES / 16;               // 1250, exact
    lognorm_main<<<dim3(gtiles), dim3(256), 0, stream>>>(
        Z_mu, Z_sigma, cwA, out);
}

// Round 10
// 16.522 us; speedup vs baseline: 1.0183x; 1.0183x over previous
//
#include <hip/hip_runtime.h>

// LogNorm moment-matching, v10: SINGLE-kernel triangular flat-K f16 GEMM.
//
//   e = exp(Z_mu + sigma^2/2); x1' = e/4; x2' = e*sigma/4        (C x G)
//   var_num'[s,g] = sum_{d<=c} sc * (w_sc w_sd corr_cd) * (x2'_c x2'_d)
//   Ssum'[s,g]    = W @ x1'; var = vn'/ss'^2 (scales cancel);
//   mu = log(ss') + log4 - var/2 ; sigma = sqrt(var)
//
// v9 post-mortem: neither reg-preload (v8) nor 2x TLP (v9) beat v7 ->
// remaining costs are the 2-dispatch fixed overhead + L2 A-stream.
// v10: A-frags rebuilt in-kernel from separable factors
//   A[s][c,d] = (sc*corr[c][d]) * w[s][c] * w[s][d]
//   - mcorr = sc*corr -> f16 LDS [64][64], built once per block (~8KB),
//     build overlaps X-phase HBM latency; K-loop reads are row-uniform
//     (broadcast across 16 lanes/quarter, 16 banks) = conflict-free.
//   - w[s][*] factors hoisted per lane (wd16[2] frags, wc16[16]).
//   - Ssum W-frags == wd16 (free).
// No build_A kernel, no d_ws, no L2 A-panel stream. Geometry = v7
// (625 blocks x 256 thr, 32 genes/block; best measured).
//
// MFMA 16x16x32_f16, layout as verified v2-v9:
//   A-frag: lane(q,gl) = A[m=gl][k=q*8+j]   (m = state)
//   B-frag: lane(q,gl) = B[k=q*8+j][n=gl]   (n = gene)
//   C/D:    lane(q,gl) reg r = D[row=q*4+r][col=gl]

#define S_STATES 16
#define C_TYPES  64
#define G_GENES  20000
#define OUT_HALF (S_STATES * G_GENES)
#define PER_WAVE 24

typedef _Float16 f16x2 __attribute__((ext_vector_type(2)));
typedef _Float16 f16x8 __attribute__((ext_vector_type(8)));
typedef float    f32x4 __attribute__((ext_vector_type(4)));

union Frag8 { f16x2 p[4]; f16x8 v; uint4 u; _Float16 h[8]; };

__global__ __launch_bounds__(256, 3)
void lognorm_fused(const float* __restrict__ Z_mu,
                   const float* __restrict__ Z_sigma,
                   const float* __restrict__ corr,
                   const float* __restrict__ w,
                   float* __restrict__ out)
{
    __shared__ _Float16 mcorr[C_TYPES][C_TYPES];  // sc*corr, f16 (8 KB)
    __shared__ f16x2 x2pT[32][35];       // [gene][d-pair]
    __shared__ f16x2 x1pT[32][35];
    __shared__ f16x2 x2tp[C_TYPES][21];  // [c][(g,g+16) pair]; broadcast
    __shared__ float accs[4][S_STATES][33];
    __shared__ float ssum_s[S_STATES][33];

    const int gt    = blockIdx.x;        // 0..624, 32 genes (exact)
    const int tid   = threadIdx.x;
    const int w4    = tid >> 6;          // wave id = K-interleave slot
    const int lane  = tid & 63;
    const int gl    = lane & 15;
    const int q     = lane >> 4;
    const int gbase = gt * 32;

    // ---- issue Z loads FIRST (HBM latency hides under mcorr build) ----
    const int dp_x = tid >> 3;
    const int ga_x = (tid & 7) * 2;
    const float* zm0 = Z_mu    + (2*dp_x) * G_GENES + gbase + ga_x;
    const float* zs0 = Z_sigma + (2*dp_x) * G_GENES + gbase + ga_x;
    const float2 m00 = *(const float2*)zm0;
    const float2 m01 = *(const float2*)(zm0 + 16);
    const float2 m10 = *(const float2*)(zm0 + G_GENES);
    const float2 m11 = *(const float2*)(zm0 + G_GENES + 16);
    const float2 s00 = *(const float2*)zs0;
    const float2 s01 = *(const float2*)(zs0 + 16);
    const float2 s10 = *(const float2*)(zs0 + G_GENES);
    const float2 s11 = *(const float2*)(zs0 + G_GENES + 16);

    // ---- mcorr build: thread -> row c = tid>>2, cols (tid&3)*16.. ----
    {
        const int c   = tid >> 2;
        const int b0c = (tid & 3) * 16;
        const float* crow = corr + c * C_TYPES + b0c;
        const float4 c0 = *(const float4*)(crow);
        const float4 c1 = *(const float4*)(crow + 4);
        const float4 c2 = *(const float4*)(crow + 8);
        const float4 c3 = *(const float4*)(crow + 12);
        const float cv[16] = {c0.x,c0.y,c0.z,c0.w, c1.x,c1.y,c1.z,c1.w,
                              c2.x,c2.y,c2.z,c2.w, c3.x,c3.y,c3.z,c3.w};
        Frag8 f0, f1;
#pragma unroll
        for (int jj = 0; jj < 8; ++jj) {
            const int d0 = b0c + jj, d1 = b0c + 8 + jj;
            const float sc0 = (d0 < c) ? 2.f : (d0 == c ? 1.f : 0.f);
            const float sc1 = (d1 < c) ? 2.f : (d1 == c ? 1.f : 0.f);
            f0.h[jj] = (_Float16)(sc0 * cv[jj]);
            f1.h[jj] = (_Float16)(sc1 * cv[8 + jj]);
        }
        *(uint4*)&mcorr[c][b0c]     = f0.u;
        *(uint4*)&mcorr[c][b0c + 8] = f1.u;
    }

    // ---- per-lane w factors (L1-resident; 4 KB total) ----
    Frag8 wd16[2];                       // (f16) w[gl][dh*32 + q*8 + j]
#pragma unroll
    for (int dh = 0; dh < 2; ++dh) {
        const float4 a = *(const float4*)(w + gl * C_TYPES + dh * 32 + q * 8);
        const float4 b = *(const float4*)(w + gl * C_TYPES + dh * 32 + q * 8 + 4);
        wd16[dh].h[0] = (_Float16)a.x; wd16[dh].h[1] = (_Float16)a.y;
        wd16[dh].h[2] = (_Float16)a.z; wd16[dh].h[3] = (_Float16)a.w;
        wd16[dh].h[4] = (_Float16)b.x; wd16[dh].h[5] = (_Float16)b.y;
        wd16[dh].h[6] = (_Float16)b.z; wd16[dh].h[7] = (_Float16)b.w;
    }
    _Float16 wc16[16];                   // (f16) w[gl][4k + w4]
#pragma unroll
    for (int k = 0; k < 16; ++k)
        wc16[k] = (_Float16)w[gl * C_TYPES + 4 * k + w4];

    // ---- X-phase compute + LDS stores ----
    {
        float x1v[2][2][2], x2v[2][2][2];   // [row r][half h][gene j]
#define XDO(r,h,j,M,S) { const float s_=(S); const float e_=__expf(fmaf(0.5f*s_,s_,(M)))*0.25f; \
                         x1v[r][h][j]=e_; x2v[r][h][j]=e_*s_; }
        XDO(0,0,0, m00.x, s00.x) XDO(0,0,1, m00.y, s00.y)
        XDO(0,1,0, m01.x, s01.x) XDO(0,1,1, m01.y, s01.y)
        XDO(1,0,0, m10.x, s10.x) XDO(1,0,1, m10.y, s10.y)
        XDO(1,1,0, m11.x, s11.x) XDO(1,1,1, m11.y, s11.y)
#undef XDO
#pragma unroll
        for (int h = 0; h < 2; ++h)
#pragma unroll
            for (int j = 0; j < 2; ++j) {
                const int g = ga_x + j + 16 * h;
                f16x2 a, b;
                a.x = (_Float16)x2v[0][h][j]; a.y = (_Float16)x2v[1][h][j];
                b.x = (_Float16)x1v[0][h][j]; b.y = (_Float16)x1v[1][h][j];
                x2pT[g][dp_x] = a;
                x1pT[g][dp_x] = b;
            }
#pragma unroll
        for (int r = 0; r < 2; ++r)
#pragma unroll
            for (int j = 0; j < 2; ++j) {
                f16x2 a;
                a.x = (_Float16)x2v[r][0][j];   // gene subtile 0
                a.y = (_Float16)x2v[r][1][j];   // gene subtile 1
                x2tp[2*dp_x + r][ga_x + j] = a;
            }
    }
    __syncthreads();

    // ---- xh: 16 LDS reads, reused 12x each ----
    f16x2 xh[2][4][2];                   // [dh][jp][t]
#pragma unroll
    for (int dh = 0; dh < 2; ++dh)
#pragma unroll
        for (int t = 0; t < 2; ++t)
#pragma unroll
            for (int jp = 0; jp < 4; ++jp)
                xh[dh][jp][t] = x2pT[gl + 16*t][dh*16 + q*4 + jp];

    // ---- K-loop: 24 x {mcorr ds_read_b128 (bcast), xct ds_read_b32,
    //      8 pk_mul A-build, 8 pk_mul B-build, 2 MFMA}; no VMEM ----
    f32x4 acc0 = {0.f,0.f,0.f,0.f}, acc1 = {0.f,0.f,0.f,0.f};
#pragma unroll
    for (int i = 0; i < PER_WAVE; ++i) {
        const int dh  = (i >= 16) ? 1 : 0;
        const int c   = i*4 + w4 - dh*32;
        const int idx = dh ? (i - 8) : i;
        Frag8 mc; mc.u = *(const uint4*)&mcorr[c][dh*32 + q*8];
        f16x2 wcp; wcp.x = wc16[idx]; wcp.y = wc16[idx];
        Frag8 af;
#pragma unroll
        for (int jp = 0; jp < 4; ++jp)
            af.p[jp] = (mc.p[jp] * wd16[dh].p[jp]) * wcp;
        const f16x2 xct = x2tp[c][gl];   // conflict-free broadcast
        f16x2 s0; s0.x = xct.x; s0.y = xct.x;
        f16x2 s1; s1.x = xct.y; s1.y = xct.y;
        Frag8 b0, b1;
#pragma unroll
        for (int jp = 0; jp < 4; ++jp) {
            b0.p[jp] = s0 * xh[dh][jp][0];
            b1.p[jp] = s1 * xh[dh][jp][1];
        }
        acc0 = __builtin_amdgcn_mfma_f32_16x16x32_f16(af.v, b0.v, acc0, 0, 0, 0);
        acc1 = __builtin_amdgcn_mfma_f32_16x16x32_f16(af.v, b1.v, acc1, 0, 0, 0);
    }
#pragma unroll
    for (int r = 0; r < 4; ++r) {
        accs[w4][q*4 + r][gl]      = acc0[r];
        accs[w4][q*4 + r][gl + 16] = acc1[r];
    }

    // ---- Ssum GEMM: waves 0,1 -> gene subtiles 0,1; W-frag == wd16 ----
    if (w4 < 2) {
        Frag8 x1f[2];
#pragma unroll
        for (int kk = 0; kk < 2; ++kk)
#pragma unroll
            for (int jp = 0; jp < 4; ++jp)
                x1f[kk].p[jp] = x1pT[gl + 16*w4][kk*16 + q*4 + jp];
        f32x4 sa = {0.f,0.f,0.f,0.f};
        sa = __builtin_amdgcn_mfma_f32_16x16x32_f16(wd16[0].v, x1f[0].v, sa, 0, 0, 0);
        sa = __builtin_amdgcn_mfma_f32_16x16x32_f16(wd16[1].v, x1f[1].v, sa, 0, 0, 0);
#pragma unroll
        for (int r = 0; r < 4; ++r) ssum_s[q*4 + r][gl + 16*w4] = sa[r];
    }
    __syncthreads();

    // ---- epilogue: thread -> (s = tid>>4, genes gx, gx+16) ----
    const int s  = tid >> 4;
    const int gx = tid & 15;
#pragma unroll
    for (int t = 0; t < 2; ++t) {
        const int gg = gx + 16 * t;
        const float vn = (accs[0][s][gg] + accs[1][s][gg])
                       + (accs[2][s][gg] + accs[3][s][gg]);
        const float ss   = ssum_s[s][gg];                 // = Ssum/4
        const float rvar = fmaxf(vn, 0.f) / (ss * ss);    // scale cancels
        out[s * G_GENES + gbase + gg] =
            __logf(ss) + 1.3862943611f - 0.5f * rvar;     // + log 4
        out[OUT_HALF + s * G_GENES + gbase + gg] = sqrtf(rvar);
    }
}

extern "C" void kernel_launch(void* const* d_in, const int* in_sizes, int n_in,
                              void* d_out, int out_size, void* d_ws, size_t ws_size,
                              hipStream_t stream) {
    const float* Z_mu      = (const float*)d_in[0];
    const float* Z_sigma   = (const float*)d_in[1];
    const float* corr      = (const float*)d_in[2];
    const float* cell_prob = (const float*)d_in[3];
    float* out = (float*)d_out;

    const int gtiles = G_GENES / 32;               // 625, exact
    lognorm_fused<<<dim3(gtiles), dim3(256), 0, stream>>>(
        Z_mu, Z_sigma, corr, cell_prob, out);
}

// Round 11
// 15.344 us; speedup vs baseline: 1.0965x; 1.0768x over previous
//
#include <hip/hip_runtime.h>

// LogNorm moment-matching, v11: v7 (best: 15.4us) + 4 blocks/CU + 4 acc
// chains. Deliberately minimal diff vs v7 — v8 (reg preload), v9 (2x TLP),
// v10 (single-kernel fusion) all regressed, isolating the residual to
// {occupancy at phase boundaries, MFMA dep-chain depth}.
//
//   e = exp(Z_mu + sigma^2/2); x1' = e/4; x2' = e*sigma/4        (C x G)
//   var_num'[s,g] = sum_{d<=c} sc * (w_sc w_sd corr_cd) * (x2'_c x2'_d)
//   Ssum'[s,g]    = W @ x1'; var = vn'/ss'^2 (scales cancel);
//   mu = log(ss') + log4 - var/2 ; sigma = sqrt(var)
//
// MFMA 16x16x32_f16, layout as verified v2-v10:
//   A-frag: lane(q,gl) = A[m=gl][k=q*8+j]   (m = state)
//   B-frag: lane(q,gl) = B[k=q*8+j][n=gl]   (n = gene)
//   C/D:    lane(q,gl) reg r = D[row=q*4+r][col=gl]

#define S_STATES 16
#define C_TYPES  64
#define G_GENES  20000
#define OUT_HALF (S_STATES * G_GENES)
#define NPAIR    96
#define PER_WAVE 24

typedef _Float16 f16x2 __attribute__((ext_vector_type(2)));
typedef _Float16 f16x8 __attribute__((ext_vector_type(8)));
typedef float    f32x4 __attribute__((ext_vector_type(4)));

union Frag8 { f16x2 p[4]; f16x8 v; uint4 u; _Float16 h[8]; };

// ---- Kernel P: frag-ordered f16 A panels (1 KB each; 98 KB total) ----
__global__ __launch_bounds__(64)
void build_A(const float* __restrict__ corr, const float* __restrict__ w,
             unsigned short* __restrict__ cwA)
{
    const int p    = blockIdx.x;          // 0..97
    const int lane = threadIdx.x;
    const int gl   = lane & 15;           // state (A row)
    const int q    = lane >> 4;
    Frag8 v;
    if (p < NPAIR) {
        const int dh = (p >= 64);
        const int c  = dh ? p - 32 : p;
        const int d0 = dh * 32 + q * 8;
        const float wc = w[gl * C_TYPES + c];
        const float4 c0 = *(const float4*)(corr + c * C_TYPES + d0);
        const float4 c1 = *(const float4*)(corr + c * C_TYPES + d0 + 4);
        const float4 w0 = *(const float4*)(w + gl * C_TYPES + d0);
        const float4 w1 = *(const float4*)(w + gl * C_TYPES + d0 + 4);
        const float cv[8] = {c0.x,c0.y,c0.z,c0.w,c1.x,c1.y,c1.z,c1.w};
        const float wv[8] = {w0.x,w0.y,w0.z,w0.w,w1.x,w1.y,w1.z,w1.w};
#pragma unroll
        for (int j = 0; j < 8; ++j) {
            const int d = d0 + j;
            const float sc = (d < c) ? 2.0f : (d == c ? 1.0f : 0.0f);
            v.h[j] = (_Float16)(sc * cv[j] * wc * wv[j]);
        }
    } else {                               // W panels for the Ssum GEMM
        const int k0 = (p - NPAIR) * 32 + q * 8;
        const float4 w0 = *(const float4*)(w + gl * C_TYPES + k0);
        const float4 w1 = *(const float4*)(w + gl * C_TYPES + k0 + 4);
        const float wv[8] = {w0.x,w0.y,w0.z,w0.w,w1.x,w1.y,w1.z,w1.w};
#pragma unroll
        for (int j = 0; j < 8; ++j) v.h[j] = (_Float16)wv[j];
    }
    *(uint4*)(cwA + (p << 9) + lane * 8) = v.u;
}

// ---- Kernel M: main ----
__global__ __launch_bounds__(256, 4)     // 4 blocks/CU (was 3)
void lognorm_main(const float* __restrict__ Z_mu,
                  const float* __restrict__ Z_sigma,
                  const unsigned short* __restrict__ cwA,
                  float* __restrict__ out)
{
    __shared__ f16x2 x2pT[32][35];       // [gene][d-pair]
    __shared__ f16x2 x1pT[32][35];
    __shared__ f16x2 x2tp[C_TYPES][21];  // [c][(g,g+16) pair]; broadcast
    __shared__ float accs[4][S_STATES][33];
    __shared__ float ssum_s[S_STATES][33];

    const int gt    = blockIdx.x;        // 0..624, 32 genes (exact)
    const int tid   = threadIdx.x;
    const int w     = tid >> 6;          // wave id = K-interleave slot
    const int lane  = tid & 63;
    const int gl    = lane & 15;
    const int q     = lane >> 4;
    const int gbase = gt * 32;

    // ---- X-phase: thread -> (d-pair dp = tid>>3, 2 genes x 2 subtiles) ----
    {
        const int dp = tid >> 3;
        const int gq = tid & 7;
        const int ga = gq * 2;
        const float* zm0 = Z_mu    + (2*dp) * G_GENES + gbase + ga;
        const float* zs0 = Z_sigma + (2*dp) * G_GENES + gbase + ga;
        const float2 m00 = *(const float2*)zm0;
        const float2 m01 = *(const float2*)(zm0 + 16);
        const float2 m10 = *(const float2*)(zm0 + G_GENES);
        const float2 m11 = *(const float2*)(zm0 + G_GENES + 16);
        const float2 s00 = *(const float2*)zs0;
        const float2 s01 = *(const float2*)(zs0 + 16);
        const float2 s10 = *(const float2*)(zs0 + G_GENES);
        const float2 s11 = *(const float2*)(zs0 + G_GENES + 16);
        float x1v[2][2][2], x2v[2][2][2];   // [row r][half h][gene j]
#define XDO(r,h,j,M,S) { const float s_=(S); const float e_=__expf(fmaf(0.5f*s_,s_,(M)))*0.25f; \
                         x1v[r][h][j]=e_; x2v[r][h][j]=e_*s_; }
        XDO(0,0,0, m00.x, s00.x) XDO(0,0,1, m00.y, s00.y)
        XDO(0,1,0, m01.x, s01.x) XDO(0,1,1, m01.y, s01.y)
        XDO(1,0,0, m10.x, s10.x) XDO(1,0,1, m10.y, s10.y)
        XDO(1,1,0, m11.x, s11.x) XDO(1,1,1, m11.y, s11.y)
#undef XDO
#pragma unroll
        for (int h = 0; h < 2; ++h)
#pragma unroll
            for (int j = 0; j < 2; ++j) {
                const int g = ga + j + 16 * h;
                f16x2 a, b;
                a.x = (_Float16)x2v[0][h][j]; a.y = (_Float16)x2v[1][h][j];
                b.x = (_Float16)x1v[0][h][j]; b.y = (_Float16)x1v[1][h][j];
                x2pT[g][dp] = a;
                x1pT[g][dp] = b;
            }
#pragma unroll
        for (int r = 0; r < 2; ++r)
#pragma unroll
            for (int j = 0; j < 2; ++j) {
                f16x2 a;
                a.x = (_Float16)x2v[r][0][j];   // gene subtile 0
                a.y = (_Float16)x2v[r][1][j];   // gene subtile 1
                x2tp[2*dp + r][ga + j] = a;
            }
    }
    __syncthreads();

    // ---- B sources: xh (16 reads, reused 12x), xct (24 broadcast) ----
    f16x2 xh[2][4][2];                   // [dh][jp][t]
#pragma unroll
    for (int dh = 0; dh < 2; ++dh)
#pragma unroll
        for (int t = 0; t < 2; ++t)
#pragma unroll
            for (int jp = 0; jp < 4; ++jp)
                xh[dh][jp][t] = x2pT[gl + 16*t][dh*16 + q*4 + jp];

    f16x2 xct[PER_WAVE];
#pragma unroll
    for (int i = 0; i < PER_WAVE; ++i) {
        const int c = i*4 + w - ((i >= 16) ? 32 : 0);
        xct[i] = x2tp[c][gl];
    }

    // ---- K-loop: 24 x {A-load(b128), 8 pk_mul, 2 MFMA}; 4 acc chains ----
    const unsigned short* Abase = cwA + (w << 9) + lane * 8;
    f32x4 acc0a = {0.f,0.f,0.f,0.f}, acc0b = {0.f,0.f,0.f,0.f};
    f32x4 acc1a = {0.f,0.f,0.f,0.f}, acc1b = {0.f,0.f,0.f,0.f};
#pragma unroll
    for (int i = 0; i < PER_WAVE; ++i) {
        Frag8 af; af.u = *(const uint4*)(Abase + (i << 11));
        const int dh = (i >= 16) ? 1 : 0;
        Frag8 b0, b1;
#pragma unroll
        for (int jp = 0; jp < 4; ++jp) {
            f16x2 s0; s0.x = xct[i].x; s0.y = xct[i].x;
            f16x2 s1; s1.x = xct[i].y; s1.y = xct[i].y;
            b0.p[jp] = s0 * xh[dh][jp][0];
            b1.p[jp] = s1 * xh[dh][jp][1];
        }
        if (i & 1) {
            acc0b = __builtin_amdgcn_mfma_f32_16x16x32_f16(af.v, b0.v, acc0b, 0, 0, 0);
            acc1b = __builtin_amdgcn_mfma_f32_16x16x32_f16(af.v, b1.v, acc1b, 0, 0, 0);
        } else {
            acc0a = __builtin_amdgcn_mfma_f32_16x16x32_f16(af.v, b0.v, acc0a, 0, 0, 0);
            acc1a = __builtin_amdgcn_mfma_f32_16x16x32_f16(af.v, b1.v, acc1a, 0, 0, 0);
        }
    }
    const f32x4 acc0 = acc0a + acc0b;
    const f32x4 acc1 = acc1a + acc1b;
#pragma unroll
    for (int r = 0; r < 4; ++r) {
        accs[w][q*4 + r][gl]      = acc0[r];
        accs[w][q*4 + r][gl + 16] = acc1[r];
    }

    // ---- Ssum GEMM: waves 0,1 -> gene subtiles 0,1 ----
    if (w < 2) {
        Frag8 wf0, wf1;
        wf0.u = *(const uint4*)(cwA + ((NPAIR + 0) << 9) + lane * 8);
        wf1.u = *(const uint4*)(cwA + ((NPAIR + 1) << 9) + lane * 8);
        Frag8 x1f[2];
#pragma unroll
        for (int kk = 0; kk < 2; ++kk)
#pragma unroll
            for (int jp = 0; jp < 4; ++jp)
                x1f[kk].p[jp] = x1pT[gl + 16*w][kk*16 + q*4 + jp];
        f32x4 sa = {0.f,0.f,0.f,0.f};
        sa = __builtin_amdgcn_mfma_f32_16x16x32_f16(wf0.v, x1f[0].v, sa, 0, 0, 0);
        sa = __builtin_amdgcn_mfma_f32_16x16x32_f16(wf1.v, x1f[1].v, sa, 0, 0, 0);
#pragma unroll
        for (int r = 0; r < 4; ++r) ssum_s[q*4 + r][gl + 16*w] = sa[r];
    }
    __syncthreads();

    // ---- epilogue: thread -> (s = tid>>4, genes gx, gx+16) ----
    const int s  = tid >> 4;
    const int gx = tid & 15;
#pragma unroll
    for (int t = 0; t < 2; ++t) {
        const int gg = gx + 16 * t;
        const float vn = (accs[0][s][gg] + accs[1][s][gg])
                       + (accs[2][s][gg] + accs[3][s][gg]);
        const float ss   = ssum_s[s][gg];                 // = Ssum/4
        const float rvar = fmaxf(vn, 0.f) / (ss * ss);    // scale cancels
        out[s * G_GENES + gbase + gg] =
            __logf(ss) + 1.3862943611f - 0.5f * rvar;     // + log 4
        out[OUT_HALF + s * G_GENES + gbase + gg] = sqrtf(rvar);
    }
}

extern "C" void kernel_launch(void* const* d_in, const int* in_sizes, int n_in,
                              void* d_out, int out_size, void* d_ws, size_t ws_size,
                              hipStream_t stream) {
    const float* Z_mu      = (const float*)d_in[0];
    const float* Z_sigma   = (const float*)d_in[1];
    const float* corr      = (const float*)d_in[2];
    const float* cell_prob = (const float*)d_in[3];
    float* out = (float*)d_out;
    unsigned short* cwA = (unsigned short*)d_ws;   // 98 KB frag-ordered f16 A

    build_A<<<dim3(NPAIR + 2), dim3(64), 0, stream>>>(corr, cell_prob, cwA);

    const int gtiles = G_GENES / 32;               // 625, exact
    lognorm_main<<<dim3(gtiles), dim3(256), 0, stream>>>(
        Z_mu, Z_sigma, cwA, out);
}